// Round 1
// baseline (4292.076 us; speedup 1.0000x reference)
//
#include <hip/hip_runtime.h>
#include <math.h>

#define D_IN 512
#define F1   16
#define F2   7

// ---------------- degree (in-degree, self-loop added later as +1) ----------------
__global__ __launch_bounds__(256) void deg_kernel(const int* __restrict__ dst,
                                                  float* __restrict__ deg, int E) {
    int t = blockIdx.x * blockDim.x + threadIdx.x;
    if (t < E) atomicAdd(&deg[dst[t]], 1.0f);
}

// deg -> dinv = rsqrt(deg + 1)   (in place)
__global__ __launch_bounds__(256) void dinv_kernel(float* __restrict__ degdinv, int n) {
    int t = blockIdx.x * blockDim.x + threadIdx.x;
    if (t < n) {
        float d = degdinv[t] + 1.0f;   // + self-loop
        degdinv[t] = rsqrtf(d);
    }
}

// ---------------- layer-1 matmul: h1 = x @ W1   [n,512]@[512,16] ----------------
// Each thread handles 4 nodes (t, t+T, t+2T, t+3T) so the wave-uniform W1 loads
// amortize over 256 FMAs per iteration.
__global__ __launch_bounds__(256) void mm1_kernel(const float* __restrict__ x,
                                                  const float* __restrict__ W1,
                                                  float* __restrict__ h1,
                                                  int n, int T) {
    int t = blockIdx.x * blockDim.x + threadIdx.x;
    if (t >= T) return;

    int idx[4];
    bool valid[4];
    const float4* xp[4];
#pragma unroll
    for (int u = 0; u < 4; ++u) {
        int nd = t + u * T;
        valid[u] = nd < n;
        idx[u] = valid[u] ? nd : 0;
        xp[u] = (const float4*)(x + (size_t)idx[u] * D_IN);
    }

    float acc[4][F1];
#pragma unroll
    for (int u = 0; u < 4; ++u)
#pragma unroll
        for (int j = 0; j < F1; ++j) acc[u][j] = 0.0f;

    for (int c = 0; c < D_IN / 4; ++c) {
        float4 av[4];
#pragma unroll
        for (int u = 0; u < 4; ++u) av[u] = xp[u][c];

        const float4* wr = (const float4*)(W1 + (size_t)c * 4 * F1);  // rows 4c..4c+3
#pragma unroll
        for (int kk = 0; kk < 4; ++kk) {
            float4 w[4];
#pragma unroll
            for (int q = 0; q < 4; ++q) w[q] = wr[kk * 4 + q];
            const float* wf = (const float*)w;
#pragma unroll
            for (int u = 0; u < 4; ++u) {
                float xe = ((const float*)&av[u])[kk];
#pragma unroll
                for (int j = 0; j < F1; ++j) acc[u][j] += xe * wf[j];
            }
        }
    }

#pragma unroll
    for (int u = 0; u < 4; ++u) {
        if (!valid[u]) continue;
        float4* outp = (float4*)(h1 + (size_t)idx[u] * F1);
#pragma unroll
        for (int q = 0; q < 4; ++q)
            outp[q] = make_float4(acc[u][4 * q + 0], acc[u][4 * q + 1],
                                  acc[u][4 * q + 2], acc[u][4 * q + 3]);
    }
}

// ---------------- layer-1 edge aggregation: acc[dst] += h1[src]*norm ----------------
__global__ __launch_bounds__(256) void agg16_kernel(const int* __restrict__ src,
                                                    const int* __restrict__ dst,
                                                    const float* __restrict__ dinv,
                                                    const float* __restrict__ h,
                                                    float* __restrict__ acc, int E) {
    int t = blockIdx.x * blockDim.x + threadIdx.x;
    if (t >= E) return;
    int s = src[t], d = dst[t];
    float nrm = dinv[s] * dinv[d];
    const float4* hr = (const float4*)(h + (size_t)s * F1);
    float* ar = acc + (size_t)d * F1;
#pragma unroll
    for (int q = 0; q < 4; ++q) {
        float4 v = hr[q];
        atomicAdd(ar + 4 * q + 0, v.x * nrm);
        atomicAdd(ar + 4 * q + 1, v.y * nrm);
        atomicAdd(ar + 4 * q + 2, v.z * nrm);
        atomicAdd(ar + 4 * q + 3, v.w * nrm);
    }
}

// finalize layer 1: acc = relu(acc + b1 + dinv^2 * h1)   (self-loop term, in place)
__global__ __launch_bounds__(256) void fin1_kernel(float* __restrict__ acc,
                                                   const float* __restrict__ h1,
                                                   const float* __restrict__ dinv,
                                                   const float* __restrict__ b1, int n) {
    int t = blockIdx.x * blockDim.x + threadIdx.x;
    if (t >= n * F1) return;
    int node = t >> 4, j = t & 15;
    float di = dinv[node];
    float v = acc[t] + b1[j] + di * di * h1[t];
    acc[t] = v > 0.0f ? v : 0.0f;
}

// ---------------- layer-2 matmul: h2 = acc1 @ W2   [n,16]@[16,7], padded stride 8 ----
__global__ __launch_bounds__(256) void mm2_kernel(const float* __restrict__ hin,
                                                  const float* __restrict__ W2,
                                                  float* __restrict__ h2, int n) {
    int t = blockIdx.x * blockDim.x + threadIdx.x;
    if (t >= n) return;
    const float4* hr = (const float4*)(hin + (size_t)t * F1);
    float hv[F1];
#pragma unroll
    for (int q = 0; q < 4; ++q) {
        float4 v = hr[q];
        hv[4 * q + 0] = v.x; hv[4 * q + 1] = v.y;
        hv[4 * q + 2] = v.z; hv[4 * q + 3] = v.w;
    }
    float acc[F2];
#pragma unroll
    for (int j = 0; j < F2; ++j) acc[j] = 0.0f;
#pragma unroll
    for (int k = 0; k < F1; ++k) {
        float xv = hv[k];
#pragma unroll
        for (int j = 0; j < F2; ++j) acc[j] += xv * W2[k * F2 + j];
    }
    float* outp = h2 + (size_t)t * 8;
#pragma unroll
    for (int j = 0; j < F2; ++j) outp[j] = acc[j];
    outp[7] = 0.0f;
}

// ---------------- layer-2 edge aggregation into d_out ----------------
__global__ __launch_bounds__(256) void agg7_kernel(const int* __restrict__ src,
                                                   const int* __restrict__ dst,
                                                   const float* __restrict__ dinv,
                                                   const float* __restrict__ h2,
                                                   float* __restrict__ out, int E) {
    int t = blockIdx.x * blockDim.x + threadIdx.x;
    if (t >= E) return;
    int s = src[t], d = dst[t];
    float nrm = dinv[s] * dinv[d];
    const float4* hr = (const float4*)(h2 + (size_t)s * 8);
    float4 v0 = hr[0], v1 = hr[1];
    float* o = out + (size_t)d * F2;
    atomicAdd(o + 0, v0.x * nrm);
    atomicAdd(o + 1, v0.y * nrm);
    atomicAdd(o + 2, v0.z * nrm);
    atomicAdd(o + 3, v0.w * nrm);
    atomicAdd(o + 4, v1.x * nrm);
    atomicAdd(o + 5, v1.y * nrm);
    atomicAdd(o + 6, v1.z * nrm);
}

// finalize layer 2: self-loop + bias, then log_softmax, in place on d_out
__global__ __launch_bounds__(256) void fin2_kernel(float* __restrict__ out,
                                                   const float* __restrict__ h2,
                                                   const float* __restrict__ dinv,
                                                   const float* __restrict__ b2, int n) {
    int t = blockIdx.x * blockDim.x + threadIdx.x;
    if (t >= n) return;
    float di = dinv[t];
    float d2 = di * di;
    const float* hp = h2 + (size_t)t * 8;
    float* op = out + (size_t)t * F2;
    float v[F2];
#pragma unroll
    for (int j = 0; j < F2; ++j) v[j] = op[j] + b2[j] + d2 * hp[j];
    float m = v[0];
#pragma unroll
    for (int j = 1; j < F2; ++j) m = fmaxf(m, v[j]);
    float sum = 0.0f;
#pragma unroll
    for (int j = 0; j < F2; ++j) sum += expf(v[j] - m);
    float lse = m + logf(sum);
#pragma unroll
    for (int j = 0; j < F2; ++j) op[j] = v[j] - lse;
}

extern "C" void kernel_launch(void* const* d_in, const int* in_sizes, int n_in,
                              void* d_out, int out_size, void* d_ws, size_t ws_size,
                              hipStream_t stream) {
    const float* x  = (const float*)d_in[0];
    const int*   ei = (const int*)d_in[1];
    const float* W1 = (const float*)d_in[2];
    const float* b1 = (const float*)d_in[3];
    const float* W2 = (const float*)d_in[4];
    const float* b2 = (const float*)d_in[5];

    int n = in_sizes[0] / D_IN;
    int E = in_sizes[1] / 2;
    const int* src = ei;
    const int* dst = ei + E;

    // workspace layout (floats)
    float* ws = (float*)d_ws;
    size_t o = 0;
    float* dinv = ws + o; o += (size_t)((n + 3) & ~3);   // deg then dinv, n floats
    float* h1   = ws + o; o += (size_t)n * F1;           // matmul1 result
    float* acc1 = ws + o; o += (size_t)n * F1;           // layer-1 aggregate (then relu'd h)
    float* h2   = ws + o; o += (size_t)n * 8;            // matmul2 result, padded to 8
    float* out  = (float*)d_out;

    const int B = 256;
    int gE = (E + B - 1) / B;
    int gN = (n + B - 1) / B;

    // zero-init accumulators (ws/d_out are poisoned 0xAA before every call)
    hipMemsetAsync(dinv, 0, (size_t)n * sizeof(float), stream);
    hipMemsetAsync(acc1, 0, (size_t)n * F1 * sizeof(float), stream);
    hipMemsetAsync(d_out, 0, (size_t)out_size * sizeof(float), stream);

    deg_kernel<<<gE, B, 0, stream>>>(dst, dinv, E);
    dinv_kernel<<<gN, B, 0, stream>>>(dinv, n);

    int T = (n + 3) / 4;
    mm1_kernel<<<(T + B - 1) / B, B, 0, stream>>>(x, W1, h1, n, T);

    agg16_kernel<<<gE, B, 0, stream>>>(src, dst, dinv, h1, acc1, E);
    fin1_kernel<<<((size_t)n * F1 + B - 1) / B, B, 0, stream>>>(acc1, h1, dinv, b1, n);

    mm2_kernel<<<gN, B, 0, stream>>>(acc1, W2, h2, n);

    agg7_kernel<<<gE, B, 0, stream>>>(src, dst, dinv, h2, out, E);
    fin2_kernel<<<gN, B, 0, stream>>>(out, h2, dinv, b2, n);
}

// Round 2
// 901.967 us; speedup vs baseline: 4.7586x; 4.7586x over previous
//
#include <hip/hip_runtime.h>
#include <math.h>

#define D_IN 512
#define F1   16
#define F2   7

// ---------------- in-degree histogram (counting-sort pass 1) ----------------
__global__ __launch_bounds__(256) void hist_kernel(const int* __restrict__ dst,
                                                   int* __restrict__ cnt, int E) {
    int t = blockIdx.x * blockDim.x + threadIdx.x;
    if (t < E) atomicAdd(&cnt[dst[t]], 1);
}

// ---------------- prefix sum (3-kernel block scan) ----------------
__global__ __launch_bounds__(256) void scan1_kernel(const int* __restrict__ cnt,
                                                    int* __restrict__ row_ptr,
                                                    int* __restrict__ blocksums, int n) {
    __shared__ int sm[256];
    int gid = blockIdx.x * 256 + threadIdx.x;
    int v = gid < n ? cnt[gid] : 0;
    sm[threadIdx.x] = v;
    __syncthreads();
    for (int off = 1; off < 256; off <<= 1) {
        int t = threadIdx.x >= off ? sm[threadIdx.x - off] : 0;
        __syncthreads();
        sm[threadIdx.x] += t;
        __syncthreads();
    }
    if (gid < n) row_ptr[gid] = sm[threadIdx.x] - v;  // exclusive within block
    if (threadIdx.x == 255) blocksums[blockIdx.x] = sm[255];
}

__global__ __launch_bounds__(512) void scan2_kernel(int* __restrict__ blocksums, int nb) {
    __shared__ int sm[512];
    int v = ((int)threadIdx.x < nb) ? blocksums[threadIdx.x] : 0;
    sm[threadIdx.x] = v;
    __syncthreads();
    for (int off = 1; off < 512; off <<= 1) {
        int t = threadIdx.x >= off ? sm[threadIdx.x - off] : 0;
        __syncthreads();
        sm[threadIdx.x] += t;
        __syncthreads();
    }
    if ((int)threadIdx.x < nb) blocksums[threadIdx.x] = sm[threadIdx.x] - v;  // exclusive
}

// add block offsets; also init cursor and dinv = rsqrt(deg+1)
__global__ __launch_bounds__(256) void scan3_kernel(int* __restrict__ row_ptr,
                                                    const int* __restrict__ blocksums,
                                                    int* __restrict__ cursor,
                                                    const int* __restrict__ cnt,
                                                    float* __restrict__ dinv, int n) {
    int gid = blockIdx.x * 256 + threadIdx.x;
    if (gid < n) {
        int rp = row_ptr[gid] + blocksums[blockIdx.x];
        row_ptr[gid] = rp;
        cursor[gid] = rp;
        dinv[gid] = rsqrtf((float)cnt[gid] + 1.0f);
    }
}

// ---------------- counting-sort pass 2: scatter src into dst-sorted adj ----------------
__global__ __launch_bounds__(256) void scatter_kernel(const int* __restrict__ src,
                                                      const int* __restrict__ dst,
                                                      int* __restrict__ cursor,
                                                      int* __restrict__ adj, int E) {
    int t = blockIdx.x * blockDim.x + threadIdx.x;
    if (t >= E) return;
    int pos = atomicAdd(&cursor[dst[t]], 1);
    adj[pos] = src[t];
}

// ---------------- layer-1 matmul: h1s = (x @ W1) * dinv[node] ----------------
__global__ __launch_bounds__(256) void mm1_kernel(const float* __restrict__ x,
                                                  const float* __restrict__ W1,
                                                  const float* __restrict__ dinv,
                                                  float* __restrict__ h1s,
                                                  int n, int T) {
    int t = blockIdx.x * blockDim.x + threadIdx.x;
    if (t >= T) return;

    int idx[4];
    bool valid[4];
    const float4* xp[4];
#pragma unroll
    for (int u = 0; u < 4; ++u) {
        int nd = t + u * T;
        valid[u] = nd < n;
        idx[u] = valid[u] ? nd : 0;
        xp[u] = (const float4*)(x + (size_t)idx[u] * D_IN);
    }

    float acc[4][F1];
#pragma unroll
    for (int u = 0; u < 4; ++u)
#pragma unroll
        for (int j = 0; j < F1; ++j) acc[u][j] = 0.0f;

    for (int c = 0; c < D_IN / 4; ++c) {
        float4 av[4];
#pragma unroll
        for (int u = 0; u < 4; ++u) av[u] = xp[u][c];

        const float4* wr = (const float4*)(W1 + (size_t)c * 4 * F1);
#pragma unroll
        for (int kk = 0; kk < 4; ++kk) {
            float4 w[4];
#pragma unroll
            for (int q = 0; q < 4; ++q) w[q] = wr[kk * 4 + q];
            const float* wf = (const float*)w;
#pragma unroll
            for (int u = 0; u < 4; ++u) {
                float xe = ((const float*)&av[u])[kk];
#pragma unroll
                for (int j = 0; j < F1; ++j) acc[u][j] += xe * wf[j];
            }
        }
    }

#pragma unroll
    for (int u = 0; u < 4; ++u) {
        if (!valid[u]) continue;
        float di = dinv[idx[u]];
        float4* outp = (float4*)(h1s + (size_t)idx[u] * F1);
#pragma unroll
        for (int q = 0; q < 4; ++q)
            outp[q] = make_float4(acc[u][4 * q + 0] * di, acc[u][4 * q + 1] * di,
                                  acc[u][4 * q + 2] * di, acc[u][4 * q + 3] * di);
    }
}

// ---------------- layer-1 gather aggregation: acc1[d] = sum h1s[adj[...]] ----------------
// 16 lanes per node, lane j = feature j.
__global__ __launch_bounds__(256) void agg1_kernel(const int* __restrict__ row_ptr,
                                                   const int* __restrict__ row_end,
                                                   const int* __restrict__ adj,
                                                   const float* __restrict__ h,
                                                   float* __restrict__ acc, int n) {
    int t = blockIdx.x * 256 + threadIdx.x;
    int node = t >> 4, j = t & 15;
    if (node >= n) return;
    int s = row_ptr[node], e = row_end[node];
    float a0 = 0.0f, a1 = 0.0f;
    int k = s;
    for (; k + 1 < e; k += 2) {
        int s0 = adj[k], s1 = adj[k + 1];
        a0 += h[(size_t)s0 * F1 + j];
        a1 += h[(size_t)s1 * F1 + j];
    }
    if (k < e) a0 += h[(size_t)adj[k] * F1 + j];
    acc[(size_t)node * F1 + j] = a0 + a1;
}

// finalize layer 1: h = relu(dinv[d]*(acc + h1s) + b1)   (in place on acc)
__global__ __launch_bounds__(256) void fin1_kernel(float* __restrict__ acc,
                                                   const float* __restrict__ h1s,
                                                   const float* __restrict__ dinv,
                                                   const float* __restrict__ b1, int n) {
    int t = blockIdx.x * blockDim.x + threadIdx.x;
    if (t >= n * F1) return;
    int node = t >> 4, j = t & 15;
    float di = dinv[node];
    float v = di * (acc[t] + h1s[t]) + b1[j];
    acc[t] = v > 0.0f ? v : 0.0f;
}

// ---------------- layer-2 matmul: h2s = (h @ W2) * dinv, padded stride 8 ----------------
__global__ __launch_bounds__(256) void mm2_kernel(const float* __restrict__ hin,
                                                  const float* __restrict__ W2,
                                                  const float* __restrict__ dinv,
                                                  float* __restrict__ h2s, int n) {
    int t = blockIdx.x * blockDim.x + threadIdx.x;
    if (t >= n) return;
    const float4* hr = (const float4*)(hin + (size_t)t * F1);
    float hv[F1];
#pragma unroll
    for (int q = 0; q < 4; ++q) {
        float4 v = hr[q];
        hv[4 * q + 0] = v.x; hv[4 * q + 1] = v.y;
        hv[4 * q + 2] = v.z; hv[4 * q + 3] = v.w;
    }
    float acc[F2];
#pragma unroll
    for (int j = 0; j < F2; ++j) acc[j] = 0.0f;
#pragma unroll
    for (int k = 0; k < F1; ++k) {
        float xv = hv[k];
#pragma unroll
        for (int j = 0; j < F2; ++j) acc[j] += xv * W2[k * F2 + j];
    }
    float di = dinv[t];
    float* outp = h2s + (size_t)t * 8;
#pragma unroll
    for (int j = 0; j < F2; ++j) outp[j] = acc[j] * di;
    outp[7] = 0.0f;
}

// ---------------- layer-2 gather aggregation (8 lanes per node, stride 8) ----------------
__global__ __launch_bounds__(256) void agg2_kernel(const int* __restrict__ row_ptr,
                                                   const int* __restrict__ row_end,
                                                   const int* __restrict__ adj,
                                                   const float* __restrict__ h,
                                                   float* __restrict__ acc, int n) {
    int t = blockIdx.x * 256 + threadIdx.x;
    int node = t >> 3, j = t & 7;
    if (node >= n) return;
    int s = row_ptr[node], e = row_end[node];
    float a0 = 0.0f, a1 = 0.0f;
    int k = s;
    for (; k + 1 < e; k += 2) {
        int s0 = adj[k], s1 = adj[k + 1];
        a0 += h[(size_t)s0 * 8 + j];
        a1 += h[(size_t)s1 * 8 + j];
    }
    if (k < e) a0 += h[(size_t)adj[k] * 8 + j];
    acc[(size_t)node * 8 + j] = a0 + a1;
}

// finalize layer 2: v = dinv[d]*(acc2 + h2s) + b2, then log_softmax -> out (stride 7)
__global__ __launch_bounds__(256) void fin2_kernel(const float* __restrict__ acc2,
                                                   const float* __restrict__ h2s,
                                                   const float* __restrict__ dinv,
                                                   const float* __restrict__ b2,
                                                   float* __restrict__ out, int n) {
    int t = blockIdx.x * blockDim.x + threadIdx.x;
    if (t >= n) return;
    float di = dinv[t];
    const float* ap = acc2 + (size_t)t * 8;
    const float* hp = h2s + (size_t)t * 8;
    float* op = out + (size_t)t * F2;
    float v[F2];
#pragma unroll
    for (int j = 0; j < F2; ++j) v[j] = di * (ap[j] + hp[j]) + b2[j];
    float m = v[0];
#pragma unroll
    for (int j = 1; j < F2; ++j) m = fmaxf(m, v[j]);
    float sum = 0.0f;
#pragma unroll
    for (int j = 0; j < F2; ++j) sum += expf(v[j] - m);
    float lse = m + logf(sum);
#pragma unroll
    for (int j = 0; j < F2; ++j) op[j] = v[j] - lse;
}

extern "C" void kernel_launch(void* const* d_in, const int* in_sizes, int n_in,
                              void* d_out, int out_size, void* d_ws, size_t ws_size,
                              hipStream_t stream) {
    const float* x  = (const float*)d_in[0];
    const int*   ei = (const int*)d_in[1];
    const float* W1 = (const float*)d_in[2];
    const float* b1 = (const float*)d_in[3];
    const float* W2 = (const float*)d_in[4];
    const float* b2 = (const float*)d_in[5];

    int n = in_sizes[0] / D_IN;
    int E = in_sizes[1] / 2;
    const int* src = ei;
    const int* dst = ei + E;

    // workspace layout (4-byte elements)
    char* ws = (char*)d_ws;
    size_t o = 0;
    int*   cnt       = (int*)(ws + o);  o += (size_t)n * 4;
    int*   row_ptr   = (int*)(ws + o);  o += (size_t)n * 4;
    int*   cursor    = (int*)(ws + o);  o += (size_t)n * 4;   // becomes row_end after scatter
    float* dinv      = (float*)(ws + o); o += (size_t)n * 4;
    int*   blocksums = (int*)(ws + o);  o += 512 * 4;
    int*   adj       = (int*)(ws + o);  o += (size_t)E * 4;
    float* h1s       = (float*)(ws + o); o += (size_t)n * F1 * 4;  // later reused as h2s
    float* acc1      = (float*)(ws + o); o += (size_t)n * F1 * 4;  // later reused as acc2
    float* h2s  = h1s;   // layer-2 matmul result (stride 8) overwrites h1s (dead after fin1... see order)
    float* acc2 = acc1 + (size_t)n * 8;  // distinct halves: acc1[0..16n) holds relu'd h; acc2 uses upper half? no:
    // NOTE: mm2 reads acc1 (relu'd h, stride 16) and writes h2s (= h1s buffer, stride 8) -> no overlap.
    // agg2 writes acc2; fin2 reads acc2 + h2s. acc2 must not overlap acc1 while mm2 reads it,
    // but agg2 runs after mm2 completes on the same stream, so reusing acc1's buffer is safe.
    acc2 = acc1;  // stride-8 use of the same buffer, after mm2 has consumed it

    float* out = (float*)d_out;

    const int B = 256;
    int gE = (E + B - 1) / B;
    int gN = (n + B - 1) / B;
    int nb = (n + 255) / 256;

    hipMemsetAsync(cnt, 0, (size_t)n * sizeof(int), stream);

    hist_kernel<<<gE, B, 0, stream>>>(dst, cnt, E);
    scan1_kernel<<<nb, 256, 0, stream>>>(cnt, row_ptr, blocksums, n);
    scan2_kernel<<<1, 512, 0, stream>>>(blocksums, nb);
    scan3_kernel<<<nb, 256, 0, stream>>>(row_ptr, blocksums, cursor, cnt, dinv, n);

    scatter_kernel<<<gE, B, 0, stream>>>(src, dst, cursor, adj, E);

    int T = (n + 3) / 4;
    mm1_kernel<<<(T + B - 1) / B, B, 0, stream>>>(x, W1, dinv, h1s, n, T);

    agg1_kernel<<<((size_t)n * F1 + B - 1) / B, B, 0, stream>>>(row_ptr, cursor, adj, h1s, acc1, n);
    fin1_kernel<<<((size_t)n * F1 + B - 1) / B, B, 0, stream>>>(acc1, h1s, dinv, b1, n);

    mm2_kernel<<<gN, B, 0, stream>>>(acc1, W2, dinv, h2s, n);

    agg2_kernel<<<((size_t)n * 8 + B - 1) / B, B, 0, stream>>>(row_ptr, cursor, adj, h2s, acc2, n);
    fin2_kernel<<<gN, B, 0, stream>>>(acc2, h2s, dinv, b2, out, n);
}